// Round 4
// baseline (494.417 us; speedup 1.0000x reference)
//
#include <hip/hip_runtime.h>
#include <math.h>

// B=4,H=16 (NH=64), S=2048, D=64, fp32 in/out.
// scores = (Q@K^T)*4096, softmax, @V.
// f16 2-plane split: QK^T = qh*kh + qh*km + qm*kh (3 MFMA terms, err ~2^-22),
// PV = f16(P) x f16(V) single plane (err ~2^-11). Q pre-scaled by 4096*log2e/64,
// K pre-scaled by 64 (avoids f16 subnormal flush; product = SC*q*k).
// Row-sum of P via ones-column appended to V (col 64 of Oacc = l).
// LDS: stride-64 rows with XOR-8 chunk swizzle -> <=2-way banks everywhere.

#define S_LEN 2048
#define D_DIM 64
#define NH 64
#define BM 128
#define BN 64
#define QTILES (S_LEN / BM)   // 16
#define KTILES (S_LEN / BN)   // 32

typedef unsigned short u16;
typedef unsigned int u32;
typedef _Float16 f16;
typedef __attribute__((ext_vector_type(8))) _Float16 f16x8;
typedef __attribute__((ext_vector_type(4))) float f32x4;

#define SC_FULL (4096.0f * 1.4426950408889634f)  // scale * log2(e)
#define QSCALE (SC_FULL / 64.0f)
#define KSCALE 64.0f

__device__ __forceinline__ float fexp2(float x) { return exp2f(x); }

union f16cv { f16 h; u16 u; };

__device__ __forceinline__ void split2h(float a, u16& hi, u16& lo) {
  f16cv ch, cl;
  ch.h = (f16)a;                 // RNE
  float r = a - (float)ch.h;     // exact
  cl.h = (f16)r;
  hi = ch.u; lo = cl.u;
}

// swizzled ushort offset within a plane: row-major, stride 64, 8-ush chunks XORed
__device__ __forceinline__ int swz(int row, int chunk) {
  return (row << 6) + (((chunk ^ (row & 7))) << 3);
}

// ---- Prepass 1: Q,K fp32 -> 2 f16 planes each (Q scaled by QSCALE, K by KSCALE) ----
__global__ void qk_split_kernel(const float* __restrict__ Q, const float* __restrict__ K,
                                u16* __restrict__ Qh, u16* __restrict__ Qm,
                                u16* __restrict__ Kh, u16* __restrict__ Km) {
  const bool isQ = blockIdx.x < 8192;
  size_t i4 = ((size_t)(blockIdx.x & 8191) * 256 + threadIdx.x) * 4;
  const float* src = isQ ? Q : K;
  u16* ph = isQ ? Qh : Kh;
  u16* pm = isQ ? Qm : Km;
  const float sc = isQ ? QSCALE : KSCALE;
  float4 v = *(const float4*)(src + i4);
  u16 h0, l0, h1, l1, h2, l2, h3, l3;
  split2h(v.x * sc, h0, l0);
  split2h(v.y * sc, h1, l1);
  split2h(v.z * sc, h2, l2);
  split2h(v.w * sc, h3, l3);
  *(uint2*)(ph + i4) = make_uint2((u32)h0 | ((u32)h1 << 16), (u32)h2 | ((u32)h3 << 16));
  *(uint2*)(pm + i4) = make_uint2((u32)l0 | ((u32)l1 << 16), (u32)l2 | ((u32)l3 << 16));
}

// ---- Prepass 2: V -> transposed f16 plane Vt[h][d][s] ----
__global__ void v_prep_kernel(const float* __restrict__ V, u16* __restrict__ Vt) {
  __shared__ float Vf[64 * 65];
  const int tid = threadIdx.x;
  const int kt = blockIdx.x, h = blockIdx.y;
  const float* V0 = V + ((size_t)h * S_LEN + kt * 64) * 64;
  const int tx = tid & 15, ty = tid >> 4;
#pragma unroll
  for (int p = 0; p < 4; ++p) {
    int r = ty + 16 * p;
    float4 v = *(const float4*)(V0 + r * 64 + tx * 4);
    Vf[r * 65 + 4 * tx + 0] = v.x;
    Vf[r * 65 + 4 * tx + 1] = v.y;
    Vf[r * 65 + 4 * tx + 2] = v.z;
    Vf[r * 65 + 4 * tx + 3] = v.w;
  }
  __syncthreads();
  const int ch = tid & 7, dr = tid >> 3;  // s-chunk, d-row (0..31)
#pragma unroll
  for (int p = 0; p < 2; ++p) {
    int d = dr + 32 * p;
    u32 w[4];
#pragma unroll
    for (int i = 0; i < 4; ++i) {
      f16cv a, b;
      a.h = (f16)Vf[(8 * ch + 2 * i) * 65 + d];
      b.h = (f16)Vf[(8 * ch + 2 * i + 1) * 65 + d];
      w[i] = (u32)a.u | ((u32)b.u << 16);
    }
    size_t o = ((size_t)h * 64 + d) * S_LEN + (size_t)kt * 64 + 8 * ch;
    *(uint4*)(Vt + o) = make_uint4(w[0], w[1], w[2], w[3]);
  }
}

// ---- Main fused attention kernel ----
// LDS (ushort units): VT plane rows 0..64 (row 64 = ones; reads of rows 65..79
// spill into K planes -> finite garbage feeding unused Oacc cols 65..79 only).
#define VT_B 0
#define K0_B 4160
#define K1_B 8256
#define P_B  12352
#define LDS_USH 20544  // 41088 bytes -> 3 blocks/CU

__global__ __launch_bounds__(256, 3)
void attn_mfma_f16(const u16* __restrict__ Qh, const u16* __restrict__ Qm,
                   const u16* __restrict__ Kh, const u16* __restrict__ Km,
                   const u16* __restrict__ Vt, float* __restrict__ O) {
  __shared__ __align__(16) u16 lds[LDS_USH];

  const int tid = threadIdx.x;
  const int lane = tid & 63;
  const int wv = tid >> 6;
  const int c = lane & 15;
  const int g = lane >> 4;
  const int h = blockIdx.x;      // head fastest -> all q-tiles of a head on one XCD
  const int qtile = blockIdx.y;

  // ---- preload Q A-frags ----
  f16x8 aqh[2][2], aqm[2][2];
#pragma unroll
  for (int m = 0; m < 2; ++m) {
    int qrow = qtile * BM + wv * 32 + m * 16 + c;
    size_t qb = ((size_t)h * S_LEN + qrow) * 64 + g * 8;
#pragma unroll
    for (int ks = 0; ks < 2; ++ks) {
      aqh[m][ks] = *(const f16x8*)(Qh + qb + ks * 32);
      aqm[m][ks] = *(const f16x8*)(Qm + qb + ks * 32);
    }
  }

  f32x4 Oacc[2][5];
  f32x4 mrow[2];
#pragma unroll
  for (int m = 0; m < 2; ++m) {
#pragma unroll
    for (int t = 0; t < 5; ++t) Oacc[m][t] = (f32x4){0.f, 0.f, 0.f, 0.f};
    mrow[m] = (f32x4){-INFINITY, -INFINITY, -INFINITY, -INFINITY};
  }

  // ones row of Vt (row 64): written once; staging only touches rows 0..63
  if (tid < 8) {
    f16cv one; one.h = (f16)1.0f;
    u32 pp = (u32)one.u | ((u32)one.u << 16);
    uint4 ov = make_uint4(pp, pp, pp, pp);
    *(uint4*)&lds[VT_B + (64 << 6) + tid * 8] = ov;  // row 64: (64&7)==0 -> no swizzle shift
  }

  const int tx8 = tid & 7, rid = tid >> 3;

  for (int kt = 0; kt < KTILES; ++kt) {
    __syncthreads();
    // ---- stage K (2 planes) + Vt (1 plane), swizzled b128 writes ----
    {
      size_t gK = ((size_t)h * S_LEN + (size_t)kt * 64) * 64 + tx8 * 8;
      size_t gV = (size_t)h * 64 * S_LEN + (size_t)kt * 64 + tx8 * 8;
#pragma unroll
      for (int p = 0; p < 2; ++p) {
        int r = rid + 32 * p;
        int d0 = swz(r, tx8);
        *(uint4*)&lds[K0_B + d0] = *(const uint4*)(Kh + gK + (size_t)r * 64);
        *(uint4*)&lds[K1_B + d0] = *(const uint4*)(Km + gK + (size_t)r * 64);
        *(uint4*)&lds[VT_B + d0] = *(const uint4*)(Vt + gV + (size_t)r * S_LEN);
      }
    }
    __syncthreads();

    // ---- matmul1: S = Q K^T, 3 split terms ----
    f32x4 S[2][4];
#pragma unroll
    for (int m = 0; m < 2; ++m)
#pragma unroll
      for (int t = 0; t < 4; ++t) S[m][t] = (f32x4){0.f, 0.f, 0.f, 0.f};

#pragma unroll
    for (int ks = 0; ks < 2; ++ks) {
#pragma unroll
      for (int t = 0; t < 4; ++t) {
        int off = swz(16 * t + c, g + 4 * ks);
        f16x8 bh = *(const f16x8*)&lds[K0_B + off];
        f16x8 bm = *(const f16x8*)&lds[K1_B + off];
#pragma unroll
        for (int m = 0; m < 2; ++m) {
          S[m][t] = __builtin_amdgcn_mfma_f32_16x16x32_f16(aqh[m][ks], bh, S[m][t], 0, 0, 0);
          S[m][t] = __builtin_amdgcn_mfma_f32_16x16x32_f16(aqh[m][ks], bm, S[m][t], 0, 0, 0);
          S[m][t] = __builtin_amdgcn_mfma_f32_16x16x32_f16(aqm[m][ks], bh, S[m][t], 0, 0, 0);
        }
      }
    }

    // ---- online softmax (scores already in exp2 units) + f16 P write ----
#pragma unroll
    for (int m = 0; m < 2; ++m) {
      f32x4 mx;
#pragma unroll
      for (int r = 0; r < 4; ++r)
        mx[r] = fmaxf(fmaxf(S[m][0][r], S[m][1][r]), fmaxf(S[m][2][r], S[m][3][r]));
#pragma unroll
      for (int r = 0; r < 4; ++r) {
        float v = mx[r];
        v = fmaxf(v, __shfl_xor(v, 1));
        v = fmaxf(v, __shfl_xor(v, 2));
        v = fmaxf(v, __shfl_xor(v, 4));
        v = fmaxf(v, __shfl_xor(v, 8));
        mx[r] = v;
      }
      f32x4 mnew, alpha;
#pragma unroll
      for (int r = 0; r < 4; ++r) {
        mnew[r] = fmaxf(mrow[m][r], mx[r]);
        alpha[r] = fexp2(mrow[m][r] - mnew[r]);  // -inf first iter -> 0
      }
      mrow[m] = mnew;
#pragma unroll
      for (int t = 0; t < 4; ++t)
#pragma unroll
        for (int r = 0; r < 4; ++r) S[m][t][r] = fexp2(S[m][t][r] - mnew[r]);
#pragma unroll
      for (int nt = 0; nt < 5; ++nt)
#pragma unroll
        for (int r = 0; r < 4; ++r) Oacc[m][nt][r] *= alpha[r];
      // P write (f16): row rq, col 16t+c, swizzled
#pragma unroll
      for (int r = 0; r < 4; ++r) {
        int rq = wv * 32 + m * 16 + 4 * g + r;
        int rowbase = (rq << 6);
        int rsw = rq & 7;
#pragma unroll
        for (int t = 0; t < 4; ++t) {
          f16cv cv; cv.h = (f16)S[m][t][r];
          int col = 16 * t + c;
          lds[P_B + rowbase + (((col >> 3) ^ rsw) << 3) + (col & 7)] = cv.u;
        }
      }
    }
    // no barrier: each wave reads back only its own P rows

    // ---- matmul2: O += P V  (nt=4 tile: col 64 = ones -> l accumulator) ----
    f16x8 ap[2][2];
#pragma unroll
    for (int m = 0; m < 2; ++m) {
      int rq = wv * 32 + m * 16 + c;
#pragma unroll
      for (int ks = 0; ks < 2; ++ks)
        ap[m][ks] = *(const f16x8*)&lds[P_B + swz(rq, g + 4 * ks)];
    }
#pragma unroll
    for (int ks = 0; ks < 2; ++ks) {
#pragma unroll
      for (int nt = 0; nt < 5; ++nt) {
        int off = swz(16 * nt + c, g + 4 * ks);  // rows 64..79 ok (finite)
        f16x8 bv = *(const f16x8*)&lds[VT_B + off];
#pragma unroll
        for (int m = 0; m < 2; ++m)
          Oacc[m][nt] = __builtin_amdgcn_mfma_f32_16x16x32_f16(ap[m][ks], bv, Oacc[m][nt], 0, 0, 0);
      }
    }
  }

  // ---- epilogue: l = Oacc[m][4] broadcast from lane c==0 of same quad; store ----
  const int src0 = lane & 48;  // lane with c==0, same g
#pragma unroll
  for (int m = 0; m < 2; ++m) {
    float inv[4];
#pragma unroll
    for (int r = 0; r < 4; ++r) {
      float l = __shfl(Oacc[m][4][r], src0);
      inv[r] = 1.0f / l;
    }
#pragma unroll
    for (int nt = 0; nt < 4; ++nt)
#pragma unroll
      for (int r = 0; r < 4; ++r) {
        int row = qtile * BM + wv * 32 + m * 16 + 4 * g + r;
        O[((size_t)h * S_LEN + row) * 64 + 16 * nt + c] = Oacc[m][nt][r] * inv[r];
      }
  }
}

// ---- Fallback: fp32 vector kernel (used only if ws too small) ----
#define LSTR 68
__global__ __launch_bounds__(256, 2)
void attn_fp32_kernel(const float* __restrict__ Q, const float* __restrict__ K,
                      const float* __restrict__ V, float* __restrict__ O) {
  __shared__ float Qs[64][LSTR];
  __shared__ float Ks[64][LSTR];
  __shared__ float Vs[64][LSTR];
  __shared__ float Ps[64][LSTR];
  const int tid = threadIdx.x;
  const int tx = tid & 15, ty = tid >> 4;
  const int qtile = blockIdx.x, head = blockIdx.y;
  const long hoff = (long)head * S_LEN * D_DIM;
  const float* Qp = Q + hoff + (long)qtile * 64 * D_DIM;
  const float* Kp = K + hoff;
  const float* Vp = V + hoff;
  float* Op = O + hoff + (long)qtile * 64 * D_DIM;
  {
    const int cc = tx * 4;
#pragma unroll
    for (int p = 0; p < 4; ++p) {
      const int r = ty + p * 16;
      *(float4*)(&Qs[r][cc]) = *(const float4*)(Qp + r * D_DIM + cc);
    }
  }
  float m_i[4], l_i[4];
  float4 o_acc[4];
#pragma unroll
  for (int i = 0; i < 4; ++i) {
    m_i[i] = -INFINITY; l_i[i] = 0.0f;
    o_acc[i] = make_float4(0.f, 0.f, 0.f, 0.f);
  }
  const float SCALE = 4096.0f;
  const float LOG2E = 1.4426950408889634f;
  for (int kt = 0; kt < S_LEN / 64; ++kt) {
    {
      const int cc = tx * 4;
      const float* Kt = Kp + kt * 64 * D_DIM;
      const float* Vv = Vp + kt * 64 * D_DIM;
#pragma unroll
      for (int p = 0; p < 4; ++p) {
        const int r = ty + p * 16;
        *(float4*)(&Ks[r][cc]) = *(const float4*)(Kt + r * D_DIM + cc);
        *(float4*)(&Vs[r][cc]) = *(const float4*)(Vv + r * D_DIM + cc);
      }
    }
    __syncthreads();
    float s[4][4];
#pragma unroll
    for (int i = 0; i < 4; ++i)
#pragma unroll
      for (int j = 0; j < 4; ++j) s[i][j] = 0.0f;
#pragma unroll
    for (int d = 0; d < D_DIM; d += 4) {
      float4 q4[4], k4[4];
#pragma unroll
      for (int i = 0; i < 4; ++i) q4[i] = *(const float4*)(&Qs[ty * 4 + i][d]);
#pragma unroll
      for (int j = 0; j < 4; ++j) k4[j] = *(const float4*)(&Ks[tx + 16 * j][d]);
#pragma unroll
      for (int i = 0; i < 4; ++i)
#pragma unroll
        for (int j = 0; j < 4; ++j) {
          s[i][j] += q4[i].x * k4[j].x; s[i][j] += q4[i].y * k4[j].y;
          s[i][j] += q4[i].z * k4[j].z; s[i][j] += q4[i].w * k4[j].w;
        }
    }
#pragma unroll
    for (int i = 0; i < 4; ++i) {
#pragma unroll
      for (int j = 0; j < 4; ++j) s[i][j] *= SCALE;
      float rm = fmaxf(fmaxf(s[i][0], s[i][1]), fmaxf(s[i][2], s[i][3]));
#pragma unroll
      for (int off = 8; off >= 1; off >>= 1) rm = fmaxf(rm, __shfl_xor(rm, off));
      const float mnew = fmaxf(m_i[i], rm);
      const float alpha = exp2f((m_i[i] - mnew) * LOG2E);
      float rs = 0.0f;
#pragma unroll
      for (int j = 0; j < 4; ++j) {
        const float p = exp2f((s[i][j] - mnew) * LOG2E);
        s[i][j] = p; rs += p;
      }
#pragma unroll
      for (int off = 8; off >= 1; off >>= 1) rs += __shfl_xor(rs, off);
      l_i[i] = l_i[i] * alpha + rs;
      m_i[i] = mnew;
      o_acc[i].x *= alpha; o_acc[i].y *= alpha; o_acc[i].z *= alpha; o_acc[i].w *= alpha;
      const int mm = ty * 4 + i;
      Ps[mm][tx] = s[i][0]; Ps[mm][tx + 16] = s[i][1];
      Ps[mm][tx + 32] = s[i][2]; Ps[mm][tx + 48] = s[i][3];
    }
    __syncthreads();
#pragma unroll
    for (int k = 0; k < 64; k += 4) {
      float4 p4[4], v4[4];
#pragma unroll
      for (int i = 0; i < 4; ++i) p4[i] = *(const float4*)(&Ps[ty * 4 + i][k]);
#pragma unroll
      for (int kk = 0; kk < 4; ++kk) v4[kk] = *(const float4*)(&Vs[k + kk][tx * 4]);
#pragma unroll
      for (int i = 0; i < 4; ++i) {
        o_acc[i].x += p4[i].x * v4[0].x + p4[i].y * v4[1].x + p4[i].z * v4[2].x + p4[i].w * v4[3].x;
        o_acc[i].y += p4[i].x * v4[0].y + p4[i].y * v4[1].y + p4[i].z * v4[2].y + p4[i].w * v4[3].y;
        o_acc[i].z += p4[i].x * v4[0].z + p4[i].y * v4[1].z + p4[i].z * v4[2].z + p4[i].w * v4[3].z;
        o_acc[i].w += p4[i].x * v4[0].w + p4[i].y * v4[1].w + p4[i].z * v4[2].w + p4[i].w * v4[3].w;
      }
    }
    __syncthreads();
  }
#pragma unroll
  for (int i = 0; i < 4; ++i) {
    const float inv = 1.0f / l_i[i];
    o_acc[i].x *= inv; o_acc[i].y *= inv; o_acc[i].z *= inv; o_acc[i].w *= inv;
    *(float4*)(Op + (ty * 4 + i) * D_DIM + tx * 4) = o_acc[i];
  }
}

extern "C" void kernel_launch(void* const* d_in, const int* in_sizes, int n_in,
                              void* d_out, int out_size, void* d_ws, size_t ws_size,
                              hipStream_t stream) {
  const float* Q = (const float*)d_in[0];
  const float* K = (const float*)d_in[1];
  const float* V = (const float*)d_in[2];
  float* O = (float*)d_out;

  const size_t P = (size_t)NH * S_LEN * D_DIM;  // 8388608 per plane
  const size_t need = 5 * P * sizeof(u16);      // 83.9 MB

  if (ws_size >= need) {
    u16* w = (u16*)d_ws;
    u16 *Qh = w, *Qm = w + P;
    u16 *Kh = w + 2 * P, *Km = w + 3 * P;
    u16 *Vt = w + 4 * P;
    qk_split_kernel<<<16384, 256, 0, stream>>>(Q, K, Qh, Qm, Kh, Km);
    v_prep_kernel<<<dim3(KTILES, NH), 256, 0, stream>>>(V, Vt);
    attn_mfma_f16<<<dim3(NH, QTILES), 256, 0, stream>>>(Qh, Qm, Kh, Km, Vt, O);
  } else {
    attn_fp32_kernel<<<dim3(S_LEN / 64, NH), 256, 0, stream>>>(Q, K, V, O);
  }
}

// Round 5
// 334.168 us; speedup vs baseline: 1.4795x; 1.4795x over previous
//
#include <hip/hip_runtime.h>
#include <math.h>

// B=4,H=16 (NH=64), S=2048, D=64, fp32 in/out.
// scores = (Q@K^T)*4096, softmax, @V.
// f16 2-plane split: QK^T = qh*kh + qh*km + qm*kh (err ~2^-22),
// PV = f16(P) x f16(V) (err ~2^-11). Q scaled by 4096*log2e/64 (in-kernel
// split), K by 64 (prepass split). V transposed to f16 in prepass.
// 512-thread blocks (8 waves, 16 q-rows each), BM=128, BN=64.
// Register-prefetch double buffer: next K/V tile loaded into VGPRs during
// compute, written to LDS after barrier. LDS exactly 40960B.
// Per-lane l accumulation; single cross-lane reduce in epilogue.

#define S_LEN 2048
#define D_DIM 64
#define NH 64
#define BM 128
#define BN 64
#define QTILES (S_LEN / BM)   // 16
#define KTILES (S_LEN / BN)   // 32

typedef unsigned short u16;
typedef unsigned int u32;
typedef _Float16 f16;
typedef __attribute__((ext_vector_type(8))) _Float16 f16x8;
typedef __attribute__((ext_vector_type(4))) float f32x4;

#define SC_FULL (4096.0f * 1.4426950408889634f)  // scale * log2(e)
#define QSCALE (SC_FULL / 64.0f)
#define KSCALE 64.0f

union f16cv { f16 h; u16 u; };

__device__ __forceinline__ void split2h(float a, u16& hi, u16& lo) {
  f16cv ch, cl;
  ch.h = (f16)a;                 // RNE
  float r = a - (float)ch.h;     // exact (Sterbenz-ish, fits f32)
  cl.h = (f16)r;
  hi = ch.u; lo = cl.u;
}

// swizzled ushort offset: row-major stride 64, 8-ush chunks XOR row&7
__device__ __forceinline__ int swz(int row, int chunk) {
  return (row << 6) + ((chunk ^ (row & 7)) << 3);
}

// ---- Prepass 1: K fp32 -> 2 f16 planes, scaled by 64 ----
__global__ void k_split_kernel(const float* __restrict__ K,
                               u16* __restrict__ Kh, u16* __restrict__ Km) {
  size_t i4 = ((size_t)blockIdx.x * 256 + threadIdx.x) * 4;
  float4 v = *(const float4*)(K + i4);
  u16 h0, l0, h1, l1, h2, l2, h3, l3;
  split2h(v.x * KSCALE, h0, l0);
  split2h(v.y * KSCALE, h1, l1);
  split2h(v.z * KSCALE, h2, l2);
  split2h(v.w * KSCALE, h3, l3);
  *(uint2*)(Kh + i4) = make_uint2((u32)h0 | ((u32)h1 << 16), (u32)h2 | ((u32)h3 << 16));
  *(uint2*)(Km + i4) = make_uint2((u32)l0 | ((u32)l1 << 16), (u32)l2 | ((u32)l3 << 16));
}

// ---- Prepass 2: V -> transposed f16 plane Vt[h][d][s] ----
__global__ void v_prep_kernel(const float* __restrict__ V, u16* __restrict__ Vt) {
  __shared__ float Vf[64 * 65];
  const int tid = threadIdx.x;
  const int kt = blockIdx.x, h = blockIdx.y;
  const float* V0 = V + ((size_t)h * S_LEN + kt * 64) * 64;
  const int tx = tid & 15, ty = tid >> 4;
#pragma unroll
  for (int p = 0; p < 4; ++p) {
    int r = ty + 16 * p;
    float4 v = *(const float4*)(V0 + r * 64 + tx * 4);
    Vf[r * 65 + 4 * tx + 0] = v.x;
    Vf[r * 65 + 4 * tx + 1] = v.y;
    Vf[r * 65 + 4 * tx + 2] = v.z;
    Vf[r * 65 + 4 * tx + 3] = v.w;
  }
  __syncthreads();
  const int ch = tid & 7, dr = tid >> 3;  // s-chunk, d-row (0..31)
#pragma unroll
  for (int p = 0; p < 2; ++p) {
    int d = dr + 32 * p;
    u32 w[4];
#pragma unroll
    for (int i = 0; i < 4; ++i) {
      f16cv a, b;
      a.h = (f16)Vf[(8 * ch + 2 * i) * 65 + d];
      b.h = (f16)Vf[(8 * ch + 2 * i + 1) * 65 + d];
      w[i] = (u32)a.u | ((u32)b.u << 16);
    }
    size_t o = ((size_t)h * 64 + d) * S_LEN + (size_t)kt * 64 + 8 * ch;
    *(uint4*)(Vt + o) = make_uint4(w[0], w[1], w[2], w[3]);
  }
}

// ---- Main fused attention kernel ----
// LDS regions (ushort units): total 20480 ush = 40960 B exactly.
#define K0_B 0
#define K1_B 4096
#define VT_B 8192
#define P_B  12288
#define LDS_USH 20480

__global__ __launch_bounds__(512, 4)
void attn_mfma_f16(const float* __restrict__ Q, const u16* __restrict__ Kh,
                   const u16* __restrict__ Km, const u16* __restrict__ Vt,
                   float* __restrict__ O) {
  __shared__ __align__(16) u16 lds[LDS_USH];

  const int tid = threadIdx.x;
  const int lane = tid & 63;
  const int wv = tid >> 6;       // 8 waves; wave wv owns q-rows wv*16..wv*16+15
  const int c = lane & 15;
  const int g = lane >> 4;
  const int h = blockIdx.x;      // head fastest: all q-tiles of a head on one XCD
  const int qtile = blockIdx.y;

  // ---- load + split Q A-frag in-kernel (fp32 -> hi/lo f16, scaled) ----
  f16x8 aqh[2], aqm[2];
  {
    int qrow = qtile * BM + wv * 16 + c;
    const float* qp = Q + ((size_t)h * S_LEN + qrow) * 64 + g * 8;
#pragma unroll
    for (int ks = 0; ks < 2; ++ks) {
      float4 a = *(const float4*)(qp + ks * 32);
      float4 b = *(const float4*)(qp + ks * 32 + 4);
      float v[8] = {a.x, a.y, a.z, a.w, b.x, b.y, b.z, b.w};
      f16x8 hi, lo;
#pragma unroll
      for (int e = 0; e < 8; ++e) {
        float q = v[e] * QSCALE;
        f16 qh = (f16)q;
        hi[e] = qh;
        lo[e] = (f16)(q - (float)qh);
      }
      aqh[ks] = hi; aqm[ks] = lo;
    }
  }

  f32x4 Oacc[4];
  f32x4 mrow = (f32x4){-INFINITY, -INFINITY, -INFINITY, -INFINITY};
  f32x4 lrow = (f32x4){0.f, 0.f, 0.f, 0.f};
#pragma unroll
  for (int t = 0; t < 4; ++t) Oacc[t] = (f32x4){0.f, 0.f, 0.f, 0.f};

  // staging role: one (row, chunk) slot per thread
  const int srow = tid >> 3;     // 0..63
  const int schk = tid & 7;      // 0..7
  const int sdst = swz(srow, schk);
  const size_t gKbase = ((size_t)h * S_LEN) * 64 + (size_t)srow * 64 + schk * 8;
  const size_t gVbase = (size_t)h * 64 * S_LEN + (size_t)srow * S_LEN + schk * 8;

  // prologue: prefetch tile 0 into registers
  uint4 rkh, rkm, rvt;
  rkh = *(const uint4*)(Kh + gKbase);
  rkm = *(const uint4*)(Km + gKbase);
  rvt = *(const uint4*)(Vt + gVbase);

  for (int kt = 0; kt < KTILES; ++kt) {
    __syncthreads();   // all waves done reading previous tile
    *(uint4*)&lds[K0_B + sdst] = rkh;
    *(uint4*)&lds[K1_B + sdst] = rkm;
    *(uint4*)&lds[VT_B + sdst] = rvt;
    __syncthreads();   // staged tile visible

    // prefetch next tile (overlaps the whole compute phase)
    if (kt + 1 < KTILES) {
      size_t gK = gKbase + (size_t)(kt + 1) * BN * 64;
      size_t gV = gVbase + (size_t)(kt + 1) * BN;
      rkh = *(const uint4*)(Kh + gK);
      rkm = *(const uint4*)(Km + gK);
      rvt = *(const uint4*)(Vt + gV);
    }

    // ---- matmul1: S = Q K^T, 3 split terms ----
    f32x4 S[4];
#pragma unroll
    for (int t = 0; t < 4; ++t) S[t] = (f32x4){0.f, 0.f, 0.f, 0.f};
#pragma unroll
    for (int ks = 0; ks < 2; ++ks) {
#pragma unroll
      for (int t = 0; t < 4; ++t) {
        int off = swz(16 * t + c, g + 4 * ks);
        f16x8 bh = *(const f16x8*)&lds[K0_B + off];
        f16x8 bm = *(const f16x8*)&lds[K1_B + off];
        S[t] = __builtin_amdgcn_mfma_f32_16x16x32_f16(aqh[ks], bh, S[t], 0, 0, 0);
        S[t] = __builtin_amdgcn_mfma_f32_16x16x32_f16(aqh[ks], bm, S[t], 0, 0, 0);
        S[t] = __builtin_amdgcn_mfma_f32_16x16x32_f16(aqm[ks], bh, S[t], 0, 0, 0);
      }
    }

    // ---- online softmax (scores already in exp2 units) ----
    f32x4 mx;
#pragma unroll
    for (int r = 0; r < 4; ++r)
      mx[r] = fmaxf(fmaxf(S[0][r], S[1][r]), fmaxf(S[2][r], S[3][r]));
#pragma unroll
    for (int r = 0; r < 4; ++r) {
      float v = mx[r];
      v = fmaxf(v, __shfl_xor(v, 1));
      v = fmaxf(v, __shfl_xor(v, 2));
      v = fmaxf(v, __shfl_xor(v, 4));
      v = fmaxf(v, __shfl_xor(v, 8));
      mx[r] = v;
    }
    f32x4 alpha;
#pragma unroll
    for (int r = 0; r < 4; ++r) {
      float mnew = fmaxf(mrow[r], mx[r]);
      alpha[r] = exp2f(mrow[r] - mnew);   // -inf first iter -> 0
      mrow[r] = mnew;
    }
#pragma unroll
    for (int t = 0; t < 4; ++t)
#pragma unroll
      for (int r = 0; r < 4; ++r) S[t][r] = exp2f(S[t][r] - mrow[r]);
    // per-lane l accumulation (no cross-lane shuffles here)
#pragma unroll
    for (int r = 0; r < 4; ++r)
      lrow[r] = lrow[r] * alpha[r] + (S[0][r] + S[1][r] + S[2][r] + S[3][r]);
#pragma unroll
    for (int t = 0; t < 4; ++t)
#pragma unroll
      for (int r = 0; r < 4; ++r) Oacc[t][r] *= alpha[r];

    // ---- P write (f16, swizzled); wave reads back only its own rows ----
#pragma unroll
    for (int r = 0; r < 4; ++r) {
      int rq = wv * 16 + 4 * g + r;
      int rowbase = (rq << 6);
      int rsw = rq & 7;
#pragma unroll
      for (int t = 0; t < 4; ++t) {
        f16cv cv; cv.h = (f16)S[t][r];
        int col = 16 * t + c;
        lds[P_B + rowbase + (((col >> 3) ^ rsw) << 3) + (col & 7)] = cv.u;
      }
    }

    // ---- matmul2: O += P V ----
    f16x8 ap[2];
    {
      int rq = wv * 16 + c;
#pragma unroll
      for (int ks = 0; ks < 2; ++ks)
        ap[ks] = *(const f16x8*)&lds[P_B + swz(rq, g + 4 * ks)];
    }
#pragma unroll
    for (int ks = 0; ks < 2; ++ks) {
#pragma unroll
      for (int nt = 0; nt < 4; ++nt) {
        f16x8 bv = *(const f16x8*)&lds[VT_B + swz(16 * nt + c, g + 4 * ks)];
        Oacc[nt] = __builtin_amdgcn_mfma_f32_16x16x32_f16(ap[ks], bv, Oacc[nt], 0, 0, 0);
      }
    }
  }

  // ---- epilogue: reduce l across the 16 row-lanes, divide, store ----
  float inv[4];
#pragma unroll
  for (int r = 0; r < 4; ++r) {
    float l = lrow[r];
    l += __shfl_xor(l, 1);
    l += __shfl_xor(l, 2);
    l += __shfl_xor(l, 4);
    l += __shfl_xor(l, 8);
    inv[r] = 1.0f / l;
  }
#pragma unroll
  for (int nt = 0; nt < 4; ++nt)
#pragma unroll
    for (int r = 0; r < 4; ++r) {
      int row = qtile * BM + wv * 16 + 4 * g + r;
      O[((size_t)h * S_LEN + row) * 64 + 16 * nt + c] = Oacc[nt][r] * inv[r];
    }
}

// ---- Fallback: fp32 vector kernel (used only if ws too small) ----
#define LSTR 68
__global__ __launch_bounds__(256, 2)
void attn_fp32_kernel(const float* __restrict__ Q, const float* __restrict__ K,
                      const float* __restrict__ V, float* __restrict__ O) {
  __shared__ float Qs[64][LSTR];
  __shared__ float Ks[64][LSTR];
  __shared__ float Vs[64][LSTR];
  __shared__ float Ps[64][LSTR];
  const int tid = threadIdx.x;
  const int tx = tid & 15, ty = tid >> 4;
  const int qtile = blockIdx.x, head = blockIdx.y;
  const long hoff = (long)head * S_LEN * D_DIM;
  const float* Qp = Q + hoff + (long)qtile * 64 * D_DIM;
  const float* Kp = K + hoff;
  const float* Vp = V + hoff;
  float* Op = O + hoff + (long)qtile * 64 * D_DIM;
  {
    const int cc = tx * 4;
#pragma unroll
    for (int p = 0; p < 4; ++p) {
      const int r = ty + p * 16;
      *(float4*)(&Qs[r][cc]) = *(const float4*)(Qp + r * D_DIM + cc);
    }
  }
  float m_i[4], l_i[4];
  float4 o_acc[4];
#pragma unroll
  for (int i = 0; i < 4; ++i) {
    m_i[i] = -INFINITY; l_i[i] = 0.0f;
    o_acc[i] = make_float4(0.f, 0.f, 0.f, 0.f);
  }
  const float SCALE = 4096.0f;
  const float LOG2E = 1.4426950408889634f;
  for (int kt = 0; kt < S_LEN / 64; ++kt) {
    {
      const int cc = tx * 4;
      const float* Kt = Kp + kt * 64 * D_DIM;
      const float* Vv = Vp + kt * 64 * D_DIM;
#pragma unroll
      for (int p = 0; p < 4; ++p) {
        const int r = ty + p * 16;
        *(float4*)(&Ks[r][cc]) = *(const float4*)(Kt + r * D_DIM + cc);
        *(float4*)(&Vs[r][cc]) = *(const float4*)(Vv + r * D_DIM + cc);
      }
    }
    __syncthreads();
    float s[4][4];
#pragma unroll
    for (int i = 0; i < 4; ++i)
#pragma unroll
      for (int j = 0; j < 4; ++j) s[i][j] = 0.0f;
#pragma unroll
    for (int d = 0; d < D_DIM; d += 4) {
      float4 q4[4], k4[4];
#pragma unroll
      for (int i = 0; i < 4; ++i) q4[i] = *(const float4*)(&Qs[ty * 4 + i][d]);
#pragma unroll
      for (int j = 0; j < 4; ++j) k4[j] = *(const float4*)(&Ks[tx + 16 * j][d]);
#pragma unroll
      for (int i = 0; i < 4; ++i)
#pragma unroll
        for (int j = 0; j < 4; ++j) {
          s[i][j] += q4[i].x * k4[j].x; s[i][j] += q4[i].y * k4[j].y;
          s[i][j] += q4[i].z * k4[j].z; s[i][j] += q4[i].w * k4[j].w;
        }
    }
#pragma unroll
    for (int i = 0; i < 4; ++i) {
#pragma unroll
      for (int j = 0; j < 4; ++j) s[i][j] *= SCALE;
      float rm = fmaxf(fmaxf(s[i][0], s[i][1]), fmaxf(s[i][2], s[i][3]));
#pragma unroll
      for (int off = 8; off >= 1; off >>= 1) rm = fmaxf(rm, __shfl_xor(rm, off));
      const float mnew = fmaxf(m_i[i], rm);
      const float alpha = exp2f((m_i[i] - mnew) * LOG2E);
      float rs = 0.0f;
#pragma unroll
      for (int j = 0; j < 4; ++j) {
        const float p = exp2f((s[i][j] - mnew) * LOG2E);
        s[i][j] = p; rs += p;
      }
#pragma unroll
      for (int off = 8; off >= 1; off >>= 1) rs += __shfl_xor(rs, off);
      l_i[i] = l_i[i] * alpha + rs;
      m_i[i] = mnew;
      o_acc[i].x *= alpha; o_acc[i].y *= alpha; o_acc[i].z *= alpha; o_acc[i].w *= alpha;
      const int mm = ty * 4 + i;
      Ps[mm][tx] = s[i][0]; Ps[mm][tx + 16] = s[i][1];
      Ps[mm][tx + 32] = s[i][2]; Ps[mm][tx + 48] = s[i][3];
    }
    __syncthreads();
#pragma unroll
    for (int k = 0; k < 64; k += 4) {
      float4 p4[4], v4[4];
#pragma unroll
      for (int i = 0; i < 4; ++i) p4[i] = *(const float4*)(&Ps[ty * 4 + i][k]);
#pragma unroll
      for (int kk = 0; kk < 4; ++kk) v4[kk] = *(const float4*)(&Vs[k + kk][tx * 4]);
#pragma unroll
      for (int i = 0; i < 4; ++i) {
        o_acc[i].x += p4[i].x * v4[0].x + p4[i].y * v4[1].x + p4[i].z * v4[2].x + p4[i].w * v4[3].x;
        o_acc[i].y += p4[i].x * v4[0].y + p4[i].y * v4[1].y + p4[i].z * v4[2].y + p4[i].w * v4[3].y;
        o_acc[i].z += p4[i].x * v4[0].z + p4[i].y * v4[1].z + p4[i].z * v4[2].z + p4[i].w * v4[3].z;
        o_acc[i].w += p4[i].x * v4[0].w + p4[i].y * v4[1].w + p4[i].z * v4[2].w + p4[i].w * v4[3].w;
      }
    }
    __syncthreads();
  }
#pragma unroll
  for (int i = 0; i < 4; ++i) {
    const float inv = 1.0f / l_i[i];
    o_acc[i].x *= inv; o_acc[i].y *= inv; o_acc[i].z *= inv; o_acc[i].w *= inv;
    *(float4*)(Op + (ty * 4 + i) * D_DIM + tx * 4) = o_acc[i];
  }
}

extern "C" void kernel_launch(void* const* d_in, const int* in_sizes, int n_in,
                              void* d_out, int out_size, void* d_ws, size_t ws_size,
                              hipStream_t stream) {
  const float* Q = (const float*)d_in[0];
  const float* K = (const float*)d_in[1];
  const float* V = (const float*)d_in[2];
  float* O = (float*)d_out;

  const size_t P = (size_t)NH * S_LEN * D_DIM;  // 8388608 per plane
  const size_t need = 3 * P * sizeof(u16);      // 50.3 MB

  if (ws_size >= need) {
    u16* w = (u16*)d_ws;
    u16 *Kh = w, *Km = w + P, *Vt = w + 2 * P;
    k_split_kernel<<<8192, 256, 0, stream>>>(K, Kh, Km);
    v_prep_kernel<<<dim3(KTILES, NH), 256, 0, stream>>>(V, Vt);
    attn_mfma_f16<<<dim3(NH, QTILES), 512, 0, stream>>>(Q, Kh, Km, Vt, O);
  } else {
    attn_fp32_kernel<<<dim3(S_LEN / 64, NH), 256, 0, stream>>>(Q, K, V, O);
  }
}

// Round 7
// 300.121 us; speedup vs baseline: 1.6474x; 1.1134x over previous
//
#include <hip/hip_runtime.h>
#include <math.h>

// B=4,H=16 (NH=64), S=2048, D=64, fp32 in/out.
// scores = (Q@K^T)*4096, softmax, @V.
// f16 2-plane split: S = qh*kh + qh*km(lo) + qm(lo)*kh (err ~2^-22),
// PV = f16(P) x f16(V). Q scaled by 4096*log2e/64 (in-kernel split),
// K by 64 (prepass), V transposed to f16 (prepass, fused into one launch).
// Round 6: 256-thr blocks, 4 waves x 32 q-rows (2 m-tiles) -> halves
// shared-fragment LDS traffic per MFMA. Matmul1 computes S^T = K*Q^T so
// each lane owns ONE q-row: 2-shuffle row-max, 1 alpha exp2, and P written
// as packed b64 (cvt_pkrtz) instead of 16 scalar b16 stores.

#define S_LEN 2048
#define D_DIM 64
#define NH 64
#define BM 128
#define BN 64
#define QTILES (S_LEN / BM)   // 16
#define KTILES (S_LEN / BN)   // 32

typedef unsigned short u16;
typedef unsigned int u32;
typedef _Float16 f16;
typedef __attribute__((ext_vector_type(8))) _Float16 f16x8;
typedef __attribute__((ext_vector_type(2))) __fp16 fp16x2;
typedef __attribute__((ext_vector_type(4))) float f32x4;

#define SC_FULL (4096.0f * 1.4426950408889634f)  // scale * log2(e)
#define QSCALE (SC_FULL / 64.0f)
#define KSCALE 64.0f

union f16cv { f16 h; u16 u; };
union pkcv { fp16x2 h; u32 u; };

__device__ __forceinline__ void split2h(float a, u16& hi, u16& lo) {
  f16cv ch, cl;
  ch.h = (f16)a;                 // RNE
  float r = a - (float)ch.h;     // exact
  cl.h = (f16)r;
  hi = ch.u; lo = cl.u;
}

// swizzled ushort offset: row-major stride 64, 8-ush chunks XOR row&7
__device__ __forceinline__ int swz(int row, int chunk) {
  return (row << 6) + ((chunk ^ (row & 7)) << 3);
}

// ---- Fused prepass: K fp32 -> 2 f16 planes (x64); V -> transposed f16 Vt[h][d][s] ----
__global__ void prep_kernel(const float* __restrict__ K, const float* __restrict__ V,
                            u16* __restrict__ Kh, u16* __restrict__ Km,
                            u16* __restrict__ Vt) {
  if (blockIdx.x < 8192) {
    size_t i4 = ((size_t)blockIdx.x * 256 + threadIdx.x) * 4;
    float4 v = *(const float4*)(K + i4);
    u16 h0, l0, h1, l1, h2, l2, h3, l3;
    split2h(v.x * KSCALE, h0, l0);
    split2h(v.y * KSCALE, h1, l1);
    split2h(v.z * KSCALE, h2, l2);
    split2h(v.w * KSCALE, h3, l3);
    *(uint2*)(Kh + i4) = make_uint2((u32)h0 | ((u32)h1 << 16), (u32)h2 | ((u32)h3 << 16));
    *(uint2*)(Km + i4) = make_uint2((u32)l0 | ((u32)l1 << 16), (u32)l2 | ((u32)l3 << 16));
  } else {
    __shared__ float Vf[64 * 65];
    const int idx = blockIdx.x - 8192;
    const int kt = idx & 31, h = idx >> 5;
    const int tid = threadIdx.x;
    const float* V0 = V + ((size_t)h * S_LEN + kt * 64) * 64;
    const int tx = tid & 15, ty = tid >> 4;
#pragma unroll
    for (int p = 0; p < 4; ++p) {
      int r = ty + 16 * p;
      float4 v = *(const float4*)(V0 + r * 64 + tx * 4);
      Vf[r * 65 + 4 * tx + 0] = v.x;
      Vf[r * 65 + 4 * tx + 1] = v.y;
      Vf[r * 65 + 4 * tx + 2] = v.z;
      Vf[r * 65 + 4 * tx + 3] = v.w;
    }
    __syncthreads();
    const int ch = tid & 7, dr = tid >> 3;
#pragma unroll
    for (int p = 0; p < 2; ++p) {
      int d = dr + 32 * p;
      u32 w[4];
#pragma unroll
      for (int i = 0; i < 4; ++i) {
        f16cv a, b;
        a.h = (f16)Vf[(8 * ch + 2 * i) * 65 + d];
        b.h = (f16)Vf[(8 * ch + 2 * i + 1) * 65 + d];
        w[i] = (u32)a.u | ((u32)b.u << 16);
      }
      size_t o = ((size_t)h * 64 + d) * S_LEN + (size_t)kt * 64 + 8 * ch;
      *(uint4*)(Vt + o) = make_uint4(w[0], w[1], w[2], w[3]);
    }
  }
}

// ---- Main fused attention kernel ----
// LDS (ushort units): K0 4096, K1 4096, VT 4096, P 8192 -> 20480 ush = 40960 B
#define K0_B 0
#define K1_B 4096
#define VT_B 8192
#define P_B  12288
#define LDS_USH 20480

__global__ __launch_bounds__(256, 3)
void attn_mfma_f16(const float* __restrict__ Q, const u16* __restrict__ Kh,
                   const u16* __restrict__ Km, const u16* __restrict__ Vt,
                   float* __restrict__ O) {
  __shared__ __align__(16) u16 lds[LDS_USH];

  const int tid = threadIdx.x;
  const int lane = tid & 63;
  const int wv = tid >> 6;       // 4 waves; wave owns q-rows wv*32 .. wv*32+31
  const int c = lane & 15;
  const int g = lane >> 4;
  const int h = blockIdx.x;      // head fastest: q-tiles of a head share an XCD
  const int qtile = blockIdx.y;

  // ---- load + split Q B-frags (2 m-tiles), fp32 -> hi/lo f16, scaled ----
  f16x8 aqh[2][2], aqm[2][2];
#pragma unroll
  for (int m = 0; m < 2; ++m) {
    int qrow = qtile * BM + wv * 32 + m * 16 + c;
    const float* qp = Q + ((size_t)h * S_LEN + qrow) * 64 + g * 8;
#pragma unroll
    for (int ks = 0; ks < 2; ++ks) {
      float4 a = *(const float4*)(qp + ks * 32);
      float4 b = *(const float4*)(qp + ks * 32 + 4);
      float v[8] = {a.x, a.y, a.z, a.w, b.x, b.y, b.z, b.w};
      f16x8 hi, lo;
#pragma unroll
      for (int e = 0; e < 8; ++e) {
        float q = v[e] * QSCALE;
        f16 qh = (f16)q;
        hi[e] = qh;
        lo[e] = (f16)(q - (float)qh);
      }
      aqh[m][ks] = hi; aqm[m][ks] = lo;
    }
  }

  f32x4 Oacc[2][4];
  float mrow[2] = {-INFINITY, -INFINITY};
  float lrow[2] = {0.f, 0.f};
#pragma unroll
  for (int m = 0; m < 2; ++m)
#pragma unroll
    for (int t = 0; t < 4; ++t) Oacc[m][t] = (f32x4){0.f, 0.f, 0.f, 0.f};

  // staging: thread handles row srow, chunks c0 and c0+4 of each plane
  const int srow = tid >> 2;     // 0..63
  const int c0 = tid & 3;
  const int d0a = swz(srow, c0), d0b = swz(srow, c0 + 4);
  const size_t gKbase = ((size_t)h * S_LEN + srow) * 64 + c0 * 8;
  const size_t gVbase = ((size_t)h * 64 + srow) * S_LEN + c0 * 8;

  // prologue: prefetch tile 0 into registers
  uint4 rk0a = *(const uint4*)(Kh + gKbase);
  uint4 rk0b = *(const uint4*)(Kh + gKbase + 32);
  uint4 rk1a = *(const uint4*)(Km + gKbase);
  uint4 rk1b = *(const uint4*)(Km + gKbase + 32);
  uint4 rva  = *(const uint4*)(Vt + gVbase);
  uint4 rvb  = *(const uint4*)(Vt + gVbase + 32);

  for (int kt = 0; kt < KTILES; ++kt) {
    __syncthreads();   // all waves done reading previous tile
    *(uint4*)&lds[K0_B + d0a] = rk0a;
    *(uint4*)&lds[K0_B + d0b] = rk0b;
    *(uint4*)&lds[K1_B + d0a] = rk1a;
    *(uint4*)&lds[K1_B + d0b] = rk1b;
    *(uint4*)&lds[VT_B + d0a] = rva;
    *(uint4*)&lds[VT_B + d0b] = rvb;
    __syncthreads();   // staged tile visible

    // prefetch next tile (overlaps compute)
    if (kt + 1 < KTILES) {
      size_t gK = gKbase + (size_t)(kt + 1) * BN * 64;
      size_t gV = gVbase + (size_t)(kt + 1) * BN;
      rk0a = *(const uint4*)(Kh + gK);
      rk0b = *(const uint4*)(Kh + gK + 32);
      rk1a = *(const uint4*)(Km + gK);
      rk1b = *(const uint4*)(Km + gK + 32);
      rva  = *(const uint4*)(Vt + gV);
      rvb  = *(const uint4*)(Vt + gV + 32);
    }

    // ---- matmul1: S^T = K Q^T (A = K frags shared across m, B = Q in regs) ----
    f32x4 S[2][4];
#pragma unroll
    for (int m = 0; m < 2; ++m)
#pragma unroll
      for (int t = 0; t < 4; ++t) S[m][t] = (f32x4){0.f, 0.f, 0.f, 0.f};
#pragma unroll
    for (int ks = 0; ks < 2; ++ks) {
#pragma unroll
      for (int t = 0; t < 4; ++t) {
        int off = swz(16 * t + c, g + 4 * ks);
        f16x8 bh = *(const f16x8*)&lds[K0_B + off];
        f16x8 bm = *(const f16x8*)&lds[K1_B + off];
#pragma unroll
        for (int m = 0; m < 2; ++m) {
          S[m][t] = __builtin_amdgcn_mfma_f32_16x16x32_f16(bh, aqh[m][ks], S[m][t], 0, 0, 0);
          S[m][t] = __builtin_amdgcn_mfma_f32_16x16x32_f16(bm, aqh[m][ks], S[m][t], 0, 0, 0);
          S[m][t] = __builtin_amdgcn_mfma_f32_16x16x32_f16(bh, aqm[m][ks], S[m][t], 0, 0, 0);
        }
      }
    }
    // lane (c,g) holds S^T[key=16t+4g+r][qrow=c] for m-tile m.

    // ---- online softmax; each lane owns one q-row (c) ----
#pragma unroll
    for (int m = 0; m < 2; ++m) {
      float mx = S[m][0][0];
#pragma unroll
      for (int t = 0; t < 4; ++t)
#pragma unroll
        for (int r = 0; r < 4; ++r) mx = fmaxf(mx, S[m][t][r]);
      mx = fmaxf(mx, __shfl_xor(mx, 16));
      mx = fmaxf(mx, __shfl_xor(mx, 32));
      float mnew = fmaxf(mrow[m], mx);
      float a = exp2f(mrow[m] - mnew);   // -inf first iter -> 0
      mrow[m] = mnew;
      float ps = 0.f;
#pragma unroll
      for (int t = 0; t < 4; ++t)
#pragma unroll
        for (int r = 0; r < 4; ++r) {
          float p = exp2f(S[m][t][r] - mnew);
          S[m][t][r] = p;
          ps += p;
        }
      lrow[m] = lrow[m] * a + ps;
      // broadcast alpha to the lanes holding Oacc rows 4g+r
      float ab[4];
#pragma unroll
      for (int r = 0; r < 4; ++r) ab[r] = __shfl(a, (lane & 48) | (4 * g + r));
#pragma unroll
      for (int nt = 0; nt < 4; ++nt)
#pragma unroll
        for (int r = 0; r < 4; ++r) Oacc[m][nt][r] *= ab[r];
      // ---- P write: rows = qrow (c), keys 16t+4g+(0..3) packed as b64 ----
      int rql = wv * 32 + m * 16 + c;
      int rowbase = rql << 6;
      int rs7 = c & 7;
#pragma unroll
      for (int t = 0; t < 4; ++t) {
        pkcv p01, p23;
        p01.h = __builtin_amdgcn_cvt_pkrtz(S[m][t][0], S[m][t][1]);
        p23.h = __builtin_amdgcn_cvt_pkrtz(S[m][t][2], S[m][t][3]);
        int chunk = 2 * t + (g >> 1);
        int off = rowbase + ((chunk ^ rs7) << 3) + 4 * (g & 1);
        *(uint2*)&lds[P_B + off] = make_uint2(p01.u, p23.u);
      }
    }
    // no barrier: P rows of this wave are written and read by this wave only

    // ---- matmul2: O += P V (A = P frags per m, B = Vt frags shared) ----
    f16x8 ap[2][2];
#pragma unroll
    for (int m = 0; m < 2; ++m) {
      int rql = wv * 32 + m * 16 + c;
#pragma unroll
      for (int ks = 0; ks < 2; ++ks)
        ap[m][ks] = *(const f16x8*)&lds[P_B + swz(rql, g + 4 * ks)];
    }
#pragma unroll
    for (int ks = 0; ks < 2; ++ks) {
#pragma unroll
      for (int nt = 0; nt < 4; ++nt) {
        f16x8 bv = *(const f16x8*)&lds[VT_B + swz(16 * nt + c, g + 4 * ks)];
#pragma unroll
        for (int m = 0; m < 2; ++m)
          Oacc[m][nt] = __builtin_amdgcn_mfma_f32_16x16x32_f16(ap[m][ks], bv, Oacc[m][nt], 0, 0, 0);
      }
    }
  }

  // ---- epilogue: full l per q-row, broadcast 1/l to Oacc rows, store ----
#pragma unroll
  for (int m = 0; m < 2; ++m) {
    float l = lrow[m];
    l += __shfl_xor(l, 16);
    l += __shfl_xor(l, 32);
    float linv = 1.0f / l;
    float lr[4];
#pragma unroll
    for (int r = 0; r < 4; ++r) lr[r] = __shfl(linv, (lane & 48) | (4 * g + r));
#pragma unroll
    for (int nt = 0; nt < 4; ++nt)
#pragma unroll
      for (int r = 0; r < 4; ++r) {
        int row = qtile * BM + wv * 32 + m * 16 + 4 * g + r;
        O[((size_t)h * S_LEN + row) * 64 + 16 * nt + c] = Oacc[m][nt][r] * lr[r];
      }
  }
}

// ---- Fallback: fp32 vector kernel (used only if ws too small) ----
#define LSTR 68
__global__ __launch_bounds__(256, 2)
void attn_fp32_kernel(const float* __restrict__ Q, const float* __restrict__ K,
                      const float* __restrict__ V, float* __restrict__ O) {
  __shared__ float Qs[64][LSTR];
  __shared__ float Ks[64][LSTR];
  __shared__ float Vs[64][LSTR];
  __shared__ float Ps[64][LSTR];
  const int tid = threadIdx.x;
  const int tx = tid & 15, ty = tid >> 4;
  const int qtile = blockIdx.x, head = blockIdx.y;
  const long hoff = (long)head * S_LEN * D_DIM;
  const float* Qp = Q + hoff + (long)qtile * 64 * D_DIM;
  const float* Kp = K + hoff;
  const float* Vp = V + hoff;
  float* Op = O + hoff + (long)qtile * 64 * D_DIM;
  {
    const int cc = tx * 4;
#pragma unroll
    for (int p = 0; p < 4; ++p) {
      const int r = ty + p * 16;
      *(float4*)(&Qs[r][cc]) = *(const float4*)(Qp + r * D_DIM + cc);
    }
  }
  float m_i[4], l_i[4];
  float4 o_acc[4];
#pragma unroll
  for (int i = 0; i < 4; ++i) {
    m_i[i] = -INFINITY; l_i[i] = 0.0f;
    o_acc[i] = make_float4(0.f, 0.f, 0.f, 0.f);
  }
  const float SCALE = 4096.0f;
  const float LOG2E = 1.4426950408889634f;
  for (int kt = 0; kt < S_LEN / 64; ++kt) {
    {
      const int cc = tx * 4;
      const float* Kt = Kp + kt * 64 * D_DIM;
      const float* Vv = Vp + kt * 64 * D_DIM;
#pragma unroll
      for (int p = 0; p < 4; ++p) {
        const int r = ty + p * 16;
        *(float4*)(&Ks[r][cc]) = *(const float4*)(Kt + r * D_DIM + cc);
        *(float4*)(&Vs[r][cc]) = *(const float4*)(Vv + r * D_DIM + cc);
      }
    }
    __syncthreads();
    float s[4][4];
#pragma unroll
    for (int i = 0; i < 4; ++i)
#pragma unroll
      for (int j = 0; j < 4; ++j) s[i][j] = 0.0f;
#pragma unroll
    for (int d = 0; d < D_DIM; d += 4) {
      float4 q4[4], k4[4];
#pragma unroll
      for (int i = 0; i < 4; ++i) q4[i] = *(const float4*)(&Qs[ty * 4 + i][d]);
#pragma unroll
      for (int j = 0; j < 4; ++j) k4[j] = *(const float4*)(&Ks[tx + 16 * j][d]);
#pragma unroll
      for (int i = 0; i < 4; ++i)
#pragma unroll
        for (int j = 0; j < 4; ++j) {
          s[i][j] += q4[i].x * k4[j].x; s[i][j] += q4[i].y * k4[j].y;
          s[i][j] += q4[i].z * k4[j].z; s[i][j] += q4[i].w * k4[j].w;
        }
    }
#pragma unroll
    for (int i = 0; i < 4; ++i) {
#pragma unroll
      for (int j = 0; j < 4; ++j) s[i][j] *= SCALE;
      float rm = fmaxf(fmaxf(s[i][0], s[i][1]), fmaxf(s[i][2], s[i][3]));
#pragma unroll
      for (int off = 8; off >= 1; off >>= 1) rm = fmaxf(rm, __shfl_xor(rm, off));
      const float mnew = fmaxf(m_i[i], rm);
      const float alpha = exp2f((m_i[i] - mnew) * LOG2E);
      float rs = 0.0f;
#pragma unroll
      for (int j = 0; j < 4; ++j) {
        const float p = exp2f((s[i][j] - mnew) * LOG2E);
        s[i][j] = p; rs += p;
      }
#pragma unroll
      for (int off = 8; off >= 1; off >>= 1) rs += __shfl_xor(rs, off);
      l_i[i] = l_i[i] * alpha + rs;
      m_i[i] = mnew;
      o_acc[i].x *= alpha; o_acc[i].y *= alpha; o_acc[i].z *= alpha; o_acc[i].w *= alpha;
      const int mm = ty * 4 + i;
      Ps[mm][tx] = s[i][0]; Ps[mm][tx + 16] = s[i][1];
      Ps[mm][tx + 32] = s[i][2]; Ps[mm][tx + 48] = s[i][3];
    }
    __syncthreads();
#pragma unroll
    for (int k = 0; k < 64; k += 4) {
      float4 p4[4], v4[4];
#pragma unroll
      for (int i = 0; i < 4; ++i) p4[i] = *(const float4*)(&Ps[ty * 4 + i][k]);
#pragma unroll
      for (int kk = 0; kk < 4; ++kk) v4[kk] = *(const float4*)(&Vs[k + kk][tx * 4]);
#pragma unroll
      for (int i = 0; i < 4; ++i) {
        o_acc[i].x += p4[i].x * v4[0].x + p4[i].y * v4[1].x + p4[i].z * v4[2].x + p4[i].w * v4[3].x;
        o_acc[i].y += p4[i].x * v4[0].y + p4[i].y * v4[1].y + p4[i].z * v4[2].y + p4[i].w * v4[3].y;
        o_acc[i].z += p4[i].x * v4[0].z + p4[i].y * v4[1].z + p4[i].z * v4[2].z + p4[i].w * v4[3].z;
        o_acc[i].w += p4[i].x * v4[0].w + p4[i].y * v4[1].w + p4[i].z * v4[2].w + p4[i].w * v4[3].w;
      }
    }
    __syncthreads();
  }
#pragma unroll
  for (int i = 0; i < 4; ++i) {
    const float inv = 1.0f / l_i[i];
    o_acc[i].x *= inv; o_acc[i].y *= inv; o_acc[i].z *= inv; o_acc[i].w *= inv;
    *(float4*)(Op + (ty * 4 + i) * D_DIM + tx * 4) = o_acc[i];
  }
}

extern "C" void kernel_launch(void* const* d_in, const int* in_sizes, int n_in,
                              void* d_out, int out_size, void* d_ws, size_t ws_size,
                              hipStream_t stream) {
  const float* Q = (const float*)d_in[0];
  const float* K = (const float*)d_in[1];
  const float* V = (const float*)d_in[2];
  float* O = (float*)d_out;

  const size_t P = (size_t)NH * S_LEN * D_DIM;  // 8388608 per plane
  const size_t need = 3 * P * sizeof(u16);      // 50.3 MB

  if (ws_size >= need) {
    u16* w = (u16*)d_ws;
    u16 *Kh = w, *Km = w + P, *Vt = w + 2 * P;
    prep_kernel<<<8192 + 2048, 256, 0, stream>>>(K, V, Kh, Km, Vt);
    attn_mfma_f16<<<dim3(NH, QTILES), 256, 0, stream>>>(Q, Kh, Km, Vt, O);
  } else {
    attn_fp32_kernel<<<dim3(S_LEN / 64, NH), 256, 0, stream>>>(Q, K, V, O);
  }
}